// Round 15
// baseline (211.977 us; speedup 1.0000x reference)
//
#include <hip/hip_runtime.h>
#include <math.h>

#define N 4096
#define NFEAT 512
#define NHID 64
#define NHEADS 8
#define P_PAIRS 65536
#define CAP 128
#define LRELU_ALPHA 0.2f
#define GEMM_BLOCKS 256
#define CSR_BLOCKS 512   // 8 waves/block, wave-per-row
#define TAIL_BLOCKS 256  // <= 256 CUs -> co-resident by construction

typedef short bf16x8 __attribute__((ext_vector_type(8)));
typedef float f32x4 __attribute__((ext_vector_type(4)));

__device__ __forceinline__ unsigned short f2bf(float f) {
  unsigned u = __float_as_uint(f);
  u = u + 0x7FFFu + ((u >> 16) & 1u);  // round-to-nearest-even
  return (unsigned short)(u >> 16);
}
__device__ __forceinline__ float bf2f(unsigned short h) {
  return __uint_as_float(((unsigned)h) << 16);
}

// LDS swizzle for [row][32-short] tiles (r8): conflict-free fragment reads.
__device__ __forceinline__ int swz(int row, int s) {
  int sl = ((row & 7) * 32 + s) ^ ((row & 7) << 3);
  return (row >> 3) * 256 + sl;
}

// ---------------- K1: weight transpose/split + barrier reset ----------------
__global__ __launch_bounds__(256) void prep_wt(const float* __restrict__ W1,
                                               const float* __restrict__ W2,
                                               unsigned short* __restrict__ w1hi,
                                               unsigned short* __restrict__ w1lo,
                                               unsigned short* __restrict__ w2hi,
                                               unsigned short* __restrict__ w2lo,
                                               int* __restrict__ barrier) {
  if (blockIdx.x == 0 && threadIdx.x < 2) barrier[threadIdx.x] = 0;
  int c = blockIdx.x;
  const float* W;
  unsigned short *hiP, *loP;
  if (c < 512) { W = W1; hiP = w1hi; loP = w1lo; }
  else         { W = W2; hiP = w2hi; loP = w2lo; c -= 512; }
  const float* Wp = W + (size_t)(c >> 6) * 512 * 64 + (c & 63);
  for (int k = threadIdx.x; k < 512; k += 256) {
    float v = Wp[(size_t)k * 64];
    unsigned short hb = f2bf(v);
    hiP[(size_t)c * 512 + k] = hb;
    loP[(size_t)c * 512 + k] = f2bf(v - bf2f(hb));
  }
}

// ---------------- GEMM body (device fn): split-precision bf16 MFMA ---------
template <bool F32A>
__device__ __forceinline__ void gemm_body(unsigned short* As, unsigned short* Bs,
                                          int mIdx, int head,
                                          const float* __restrict__ Af,
                                          const unsigned short* __restrict__ Ahi,
                                          const unsigned short* __restrict__ Alo,
                                          const unsigned short* __restrict__ Bhi,
                                          const unsigned short* __restrict__ Blo,
                                          const float* __restrict__ aVec,
                                          float* __restrict__ C,
                                          float* __restrict__ esrc,
                                          float* __restrict__ edst,
                                          float* __restrict__ cpart) {
  const int t = threadIdx.x;
  const int m0 = mIdx * 128;
  const int c0 = head * 64;
  const int lane = t & 63, wave = t >> 6;
  const int g = lane >> 4, r = lane & 15;
  const int wm = (wave >> 1) * 32;
  const int wn = (wave & 1) * 32;
  const int sar = t >> 2, sak = (t & 3) * 8;
  const int tb = t & 255;
  const int sbr = tb >> 2, sbk = (tb & 3) * 8;
  const unsigned short* Bsel = (t < 256) ? Bhi : Blo;
  const int bhalf = (t < 256) ? 0 : 1;
  const int idxA = swz(sar, sak);
  const int idxB = swz(sbr, sbk);
  const size_t aOff = (size_t)(m0 + sar) * 512 + sak;
  const size_t bOff = (size_t)(c0 + sbr) * 512 + sbk;
  const f32x4 z = {0.f, 0.f, 0.f, 0.f};
  f32x4 acc[2][2];
  acc[0][0] = z; acc[0][1] = z; acc[1][0] = z; acc[1][1] = z;

  int4 a0, a1, b0;
  auto loadRegs = [&](int kb) {
    if constexpr (F32A) {
      float4 v0 = *(const float4*)(Af + aOff + kb);
      float4 v1 = *(const float4*)(Af + aOff + kb + 4);
      unsigned h0 = f2bf(v0.x), h1 = f2bf(v0.y), h2 = f2bf(v0.z), h3 = f2bf(v0.w);
      unsigned h4 = f2bf(v1.x), h5 = f2bf(v1.y), h6 = f2bf(v1.z), h7 = f2bf(v1.w);
      unsigned l0 = f2bf(v0.x - bf2f(h0)), l1 = f2bf(v0.y - bf2f(h1));
      unsigned l2 = f2bf(v0.z - bf2f(h2)), l3 = f2bf(v0.w - bf2f(h3));
      unsigned l4 = f2bf(v1.x - bf2f(h4)), l5 = f2bf(v1.y - bf2f(h5));
      unsigned l6 = f2bf(v1.z - bf2f(h6)), l7 = f2bf(v1.w - bf2f(h7));
      a0.x = h0 | (h1 << 16); a0.y = h2 | (h3 << 16);
      a0.z = h4 | (h5 << 16); a0.w = h6 | (h7 << 16);
      a1.x = l0 | (l1 << 16); a1.y = l2 | (l3 << 16);
      a1.z = l4 | (l5 << 16); a1.w = l6 | (l7 << 16);
    } else {
      a0 = *(const int4*)(Ahi + aOff + kb);
      a1 = *(const int4*)(Alo + aOff + kb);
    }
    b0 = *(const int4*)(Bsel + bOff + kb);
  };
  auto storeLds = [&](int buf) {
    *(int4*)(&As[(buf * 2 + 0) * 4096 + idxA]) = a0;
    *(int4*)(&As[(buf * 2 + 1) * 4096 + idxA]) = a1;
    *(int4*)(&Bs[(buf * 2 + bhalf) * 2048 + idxB]) = b0;
  };

  loadRegs(0);
  storeLds(0);
  __syncthreads();

  for (int ch = 0; ch < 16; ++ch) {
    const int cur = ch & 1;
    if (ch < 15) loadRegs((ch + 1) * 32);
    bf16x8 ah[2], al[2], bh[2], bl[2];
#pragma unroll
    for (int f = 0; f < 2; ++f) {
      int ia = swz(wm + f * 16 + r, 8 * g);
      int ib = swz(wn + f * 16 + r, 8 * g);
      ah[f] = *(const bf16x8*)(&As[(cur * 2 + 0) * 4096 + ia]);
      al[f] = *(const bf16x8*)(&As[(cur * 2 + 1) * 4096 + ia]);
      bh[f] = *(const bf16x8*)(&Bs[(cur * 2 + 0) * 2048 + ib]);
      bl[f] = *(const bf16x8*)(&Bs[(cur * 2 + 1) * 2048 + ib]);
    }
#pragma unroll
    for (int i = 0; i < 2; ++i)
#pragma unroll
      for (int j = 0; j < 2; ++j) {
        acc[i][j] = __builtin_amdgcn_mfma_f32_16x16x32_bf16(ah[i], bh[j], acc[i][j], 0, 0, 0);
        acc[i][j] = __builtin_amdgcn_mfma_f32_16x16x32_bf16(al[i], bh[j], acc[i][j], 0, 0, 0);
        acc[i][j] = __builtin_amdgcn_mfma_f32_16x16x32_bf16(ah[i], bl[j], acc[i][j], 0, 0, 0);
      }
    if (ch < 15) {
      storeLds(cur ^ 1);
      __syncthreads();
    }
  }

  // epilogue: C tile via LDS, esrc/edst shfl-dots, per-block column partials
  __syncthreads();
  float* Cs = (float*)As;  // 32 KB = 128x64 f32
#pragma unroll
  for (int i = 0; i < 2; ++i)
#pragma unroll
    for (int j = 0; j < 2; ++j)
#pragma unroll
      for (int q = 0; q < 4; ++q)
        Cs[(wm + i * 16 + 4 * g + q) * 64 + wn + j * 16 + r] = acc[i][j][q];
  __syncthreads();
  float* Cp = C + ((size_t)head * N + m0) * 64;
  const float* aV = aVec + (size_t)head * 128;
  float as_ = aV[lane], ad_ = aV[64 + lane];
  float cs = 0.f;
#pragma unroll
  for (int rr = 0; rr < 16; ++rr) {
    int row = wave * 16 + rr;
    float v = Cs[row * 64 + lane];
    Cp[(size_t)row * 64 + lane] = v;
    cs += v;
    float s = v * as_, d = v * ad_;
#pragma unroll
    for (int off = 32; off; off >>= 1) {
      s += __shfl_xor(s, off);
      d += __shfl_xor(d, off);
    }
    if (lane == 0) {
      esrc[(size_t)head * N + m0 + row] = s;
      edst[(size_t)head * N + m0 + row] = d;
    }
  }
  float* red = (float*)Bs;  // free after MFMA loop
  red[wave * 64 + lane] = cs;
  __syncthreads();
  if (wave == 0) {
    float s = 0.f;
#pragma unroll
    for (int j = 0; j < 8; ++j) s += red[j * 64 + lane];
    cpart[((size_t)head * 32 + mIdx) * 64 + lane] = s;
  }
}

// ---------------- K2: front — layer-1 GEMM + wave-per-row ballot CSR -------
__global__ __launch_bounds__(512) void front(const float* __restrict__ x,
                                             const float* __restrict__ adj,
                                             const unsigned short* __restrict__ w1hi,
                                             const unsigned short* __restrict__ w1lo,
                                             const float* __restrict__ aVec,
                                             float* __restrict__ Wh1,
                                             float* __restrict__ es1,
                                             float* __restrict__ ed1,
                                             float* __restrict__ cpart1,
                                             int* __restrict__ counts,
                                             int* __restrict__ cols) {
  __shared__ unsigned short As[2 * 2 * 4096];
  __shared__ unsigned short Bs[2 * 2 * 2048];
  int b = blockIdx.x;
  if (b >= GEMM_BLOCKS) {
    // CSR: wave-per-row ballot compaction, no atomics, no barriers.
    int lane = threadIdx.x & 63;
    int row = (b - GEMM_BLOCKS) * 8 + (threadIdx.x >> 6);
    const float4* arow = (const float4*)(adj + (size_t)row * N);
    int* crow = cols + (size_t)row * CAP;
    unsigned long long below = (1ULL << lane) - 1;
    int cnt = 0;
#pragma unroll 4
    for (int it = 0; it < 16; ++it) {
      float4 v = arow[it * 64 + lane];
      int base = (it * 64 + lane) * 4;
#pragma unroll
      for (int j = 0; j < 4; ++j) {
        float f = (j == 0) ? v.x : (j == 1) ? v.y : (j == 2) ? v.z : v.w;
        unsigned long long mask = __ballot(f > 0.f);
        if (f > 0.f) {
          int pos = cnt + __popcll(mask & below);
          if (pos < CAP) crow[pos] = base + j;
        }
        cnt += __popcll(mask);
      }
    }
    if (lane == 0) counts[row] = cnt < CAP ? cnt : CAP;
    return;
  }
  gemm_body<true>(As, Bs, b & 31, b >> 5, x, nullptr, nullptr, w1hi, w1lo,
                  aVec, Wh1, es1, ed1, cpart1);
}

// ---------------- K3: layer-1 attention, wave per (node,head) --------------
__global__ __launch_bounds__(256) void gat_attn_l1(const float* __restrict__ Wh,
                                                   const float* __restrict__ esrc,
                                                   const float* __restrict__ edst,
                                                   const int* __restrict__ counts,
                                                   const int* __restrict__ cols,
                                                   const float* __restrict__ cpart1,
                                                   unsigned short* __restrict__ hhi,
                                                   unsigned short* __restrict__ hlo) {
  int h = blockIdx.x & 7;
  int wv = threadIdx.x >> 6;
  int lane = threadIdx.x & 63;
  int sg = lane >> 4, sl = lane & 15;
  int i = (blockIdx.x >> 3) * 4 + wv;
  int cnt = counts[i];
  __shared__ int jls[4][CAP];
  __shared__ float pls[4][CAP];
  const float* WhH = Wh + (size_t)h * N * 64;
  float4 acc = {0.f, 0.f, 0.f, 0.f};
  if (cnt == 0) {
    float4 sv = {0.f, 0.f, 0.f, 0.f};
    for (int j = 0; j < 32; ++j) {
      float4 p = *(const float4*)(cpart1 + ((size_t)h * 32 + j) * 64 + 4 * sl);
      sv.x += p.x; sv.y += p.y; sv.z += p.z; sv.w += p.w;
    }
    acc.x = sv.x * (1.0f / N); acc.y = sv.y * (1.0f / N);
    acc.z = sv.z * (1.0f / N); acc.w = sv.w * (1.0f / N);
  } else {
    const int* cl = cols + (size_t)i * CAP;
    jls[wv][lane] = (lane < cnt) ? cl[lane] : 0;
    jls[wv][lane + 64] = (lane + 64 < cnt) ? cl[lane + 64] : 0;
    float ei = esrc[h * N + i];
    const float* ed = edst + (size_t)h * N;
    float e0 = -1e30f, e1 = -1e30f;
    if (lane < cnt) {
      float e = ei + ed[jls[wv][lane]];
      e0 = (e > 0.f) ? e : LRELU_ALPHA * e;
    }
    if (lane + 64 < cnt) {
      float e = ei + ed[jls[wv][lane + 64]];
      e1 = (e > 0.f) ? e : LRELU_ALPHA * e;
    }
    float m = fmaxf(e0, e1);
#pragma unroll
    for (int off = 32; off; off >>= 1) m = fmaxf(m, __shfl_xor(m, off));
    float p0 = (lane < cnt) ? __expf(e0 - m) : 0.f;
    float p1 = (lane + 64 < cnt) ? __expf(e1 - m) : 0.f;
    float ssum = p0 + p1;
#pragma unroll
    for (int off = 32; off; off >>= 1) ssum += __shfl_xor(ssum, off);
    pls[wv][lane] = p0;
    pls[wv][lane + 64] = p1;  // own-wave write->read
    int L = (cnt + 15) & ~15;
    for (int k = 0; k < L; k += 16) {
      int j0 = jls[wv][k + sg];
      int j1 = jls[wv][k + 4 + sg];
      int j2 = jls[wv][k + 8 + sg];
      int j3 = jls[wv][k + 12 + sg];
      float4 v0 = *(const float4*)(WhH + ((size_t)j0 << 6) + 4 * sl);
      float4 v1 = *(const float4*)(WhH + ((size_t)j1 << 6) + 4 * sl);
      float4 v2 = *(const float4*)(WhH + ((size_t)j2 << 6) + 4 * sl);
      float4 v3 = *(const float4*)(WhH + ((size_t)j3 << 6) + 4 * sl);
      float q0 = pls[wv][k + sg];
      float q1 = pls[wv][k + 4 + sg];
      float q2 = pls[wv][k + 8 + sg];
      float q3 = pls[wv][k + 12 + sg];
      acc.x = fmaf(q0, v0.x, acc.x); acc.y = fmaf(q0, v0.y, acc.y);
      acc.z = fmaf(q0, v0.z, acc.z); acc.w = fmaf(q0, v0.w, acc.w);
      acc.x = fmaf(q1, v1.x, acc.x); acc.y = fmaf(q1, v1.y, acc.y);
      acc.z = fmaf(q1, v1.z, acc.z); acc.w = fmaf(q1, v1.w, acc.w);
      acc.x = fmaf(q2, v2.x, acc.x); acc.y = fmaf(q2, v2.y, acc.y);
      acc.z = fmaf(q2, v2.z, acc.z); acc.w = fmaf(q2, v2.w, acc.w);
      acc.x = fmaf(q3, v3.x, acc.x); acc.y = fmaf(q3, v3.y, acc.y);
      acc.z = fmaf(q3, v3.z, acc.z); acc.w = fmaf(q3, v3.w, acc.w);
    }
    acc.x += __shfl_xor(acc.x, 16); acc.y += __shfl_xor(acc.y, 16);
    acc.z += __shfl_xor(acc.z, 16); acc.w += __shfl_xor(acc.w, 16);
    acc.x += __shfl_xor(acc.x, 32); acc.y += __shfl_xor(acc.y, 32);
    acc.z += __shfl_xor(acc.z, 32); acc.w += __shfl_xor(acc.w, 32);
    float inv = 1.0f / ssum;
    acc.x *= inv; acc.y *= inv; acc.z *= inv; acc.w *= inv;
  }
  if (sg == 0) {
    acc.x = (acc.x > 0.f) ? acc.x : expm1f(acc.x);
    acc.y = (acc.y > 0.f) ? acc.y : expm1f(acc.y);
    acc.z = (acc.z > 0.f) ? acc.z : expm1f(acc.z);
    acc.w = (acc.w > 0.f) ? acc.w : expm1f(acc.w);
    ushort4 hi4, lo4;
    hi4.x = f2bf(acc.x); lo4.x = f2bf(acc.x - bf2f(hi4.x));
    hi4.y = f2bf(acc.y); lo4.y = f2bf(acc.y - bf2f(hi4.y));
    hi4.z = f2bf(acc.z); lo4.z = f2bf(acc.z - bf2f(hi4.z));
    hi4.w = f2bf(acc.w); lo4.w = f2bf(acc.w - bf2f(hi4.w));
    size_t o = (size_t)i * 512 + h * 64 + 4 * sl;
    *(ushort4*)(hhi + o) = hi4;
    *(ushort4*)(hlo + o) = lo4;
  }
}

// ---------------- K4: tail2 — L2 GEMM + attn_l2 + score (1 kernel) ---------
// 256 blocks (1/CU guaranteed resident). Grid barriers with s_sleep backoff
// (r11 lesson: no-backoff agent-scope polling starved arrivals; 256 pollers
// at ~2k-cycle intervals are harmless).
__global__ __launch_bounds__(512) void tail2(const unsigned short* __restrict__ h1hi,
                                             const unsigned short* __restrict__ h1lo,
                                             const unsigned short* __restrict__ w2hi,
                                             const unsigned short* __restrict__ w2lo,
                                             const float* __restrict__ aVec,
                                             float* __restrict__ Wh2,
                                             float* __restrict__ es2,
                                             float* __restrict__ ed2,
                                             float* __restrict__ cpart2,
                                             const int* __restrict__ counts,
                                             const int* __restrict__ cols,
                                             const float* __restrict__ Wsc,
                                             const int* __restrict__ p1,
                                             const int* __restrict__ p2,
                                             float* __restrict__ hf,
                                             float* __restrict__ g,
                                             float* __restrict__ out,
                                             int* __restrict__ barrier) {
  __shared__ unsigned char smem[49152];  // 48 KB
  unsigned short* As = (unsigned short*)smem;            // gemm: 32 KB
  unsigned short* Bs = (unsigned short*)(smem + 32768);  // gemm: 16 KB
  const int t = threadIdx.x;

  // ---- phase 1: layer-2 GEMM on blocks 0..31 ----
  if (blockIdx.x < 32)
    gemm_body<false>(As, Bs, blockIdx.x, 0, nullptr, h1hi, h1lo, w2hi, w2lo,
                     aVec, Wh2, es2, ed2, cpart2);
  __syncthreads();

  // load W_score into LDS (overlays As; gemm blocks are done with it).
  // Non-gemm blocks do this immediately — overlapped with barrier wait.
  float* Ws = (float*)smem;  // [64][64], 16 KB
#pragma unroll
  for (int j = 0; j < 2; ++j) {
    int q = t + j * 512;
    *(float4*)(&Ws[(q >> 4) * 64 + (q & 15) * 4]) =
        *(const float4*)(Wsc + (q >> 4) * 64 + (q & 15) * 4);
  }

  // ---- grid barrier 1 (Wh2/es2/ed2/cpart2 ready) ----
  __threadfence();
  if (t == 0) {
    __hip_atomic_fetch_add(&barrier[0], 1, __ATOMIC_ACQ_REL, __HIP_MEMORY_SCOPE_AGENT);
    while (__hip_atomic_load(&barrier[0], __ATOMIC_ACQUIRE, __HIP_MEMORY_SCOPE_AGENT) <
           TAIL_BLOCKS)
      __builtin_amdgcn_s_sleep(32);
  }
  __syncthreads();

  // ---- phase 2: layer-2 attention + fused score-GEMM, 2 nodes/wave ----
  int* jls = (int*)(smem + 16384);              // [8][CAP] 4 KB
  float* pls = (float*)(smem + 16384 + 4096);   // [8][CAP] 4 KB
  int wv = t >> 6;
  int lane = t & 63;
  int sg = lane >> 4, sl = lane & 15;
  int* jw = jls + wv * CAP;
  float* pw = pls + wv * CAP;
  for (int ii = 0; ii < 2; ++ii) {
    int i = blockIdx.x * 16 + wv * 2 + ii;
    int cnt = counts[i];
    float v;
    if (cnt == 0) {
      float s = 0.f;
      for (int j = 0; j < 32; ++j) s += cpart2[(size_t)j * 64 + lane];
      v = s * (1.0f / N);
    } else {
      const int* cl = cols + (size_t)i * CAP;
      jw[lane] = (lane < cnt) ? cl[lane] : 0;
      jw[lane + 64] = (lane + 64 < cnt) ? cl[lane + 64] : 0;
      float ei = es2[i];
      float e0 = -1e30f, e1 = -1e30f;
      if (lane < cnt) {
        float e = ei + ed2[jw[lane]];
        e0 = (e > 0.f) ? e : LRELU_ALPHA * e;
      }
      if (lane + 64 < cnt) {
        float e = ei + ed2[jw[lane + 64]];
        e1 = (e > 0.f) ? e : LRELU_ALPHA * e;
      }
      float m = fmaxf(e0, e1);
#pragma unroll
      for (int off = 32; off; off >>= 1) m = fmaxf(m, __shfl_xor(m, off));
      float p0 = (lane < cnt) ? __expf(e0 - m) : 0.f;
      float p1 = (lane + 64 < cnt) ? __expf(e1 - m) : 0.f;
      float ssum = p0 + p1;
#pragma unroll
      for (int off = 32; off; off >>= 1) ssum += __shfl_xor(ssum, off);
      pw[lane] = p0;
      pw[lane + 64] = p1;  // own-wave write->read
      float4 acc = {0.f, 0.f, 0.f, 0.f};
      int L = (cnt + 15) & ~15;
      for (int k = 0; k < L; k += 16) {
        int j0 = jw[k + sg];
        int j1 = jw[k + 4 + sg];
        int j2 = jw[k + 8 + sg];
        int j3 = jw[k + 12 + sg];
        float4 v0 = *(const float4*)(Wh2 + ((size_t)j0 << 6) + 4 * sl);
        float4 v1 = *(const float4*)(Wh2 + ((size_t)j1 << 6) + 4 * sl);
        float4 v2 = *(const float4*)(Wh2 + ((size_t)j2 << 6) + 4 * sl);
        float4 v3 = *(const float4*)(Wh2 + ((size_t)j3 << 6) + 4 * sl);
        float q0 = pw[k + sg];
        float q1 = pw[k + 4 + sg];
        float q2 = pw[k + 8 + sg];
        float q3 = pw[k + 12 + sg];
        acc.x = fmaf(q0, v0.x, acc.x); acc.y = fmaf(q0, v0.y, acc.y);
        acc.z = fmaf(q0, v0.z, acc.z); acc.w = fmaf(q0, v0.w, acc.w);
        acc.x = fmaf(q1, v1.x, acc.x); acc.y = fmaf(q1, v1.y, acc.y);
        acc.z = fmaf(q1, v1.z, acc.z); acc.w = fmaf(q1, v1.w, acc.w);
        acc.x = fmaf(q2, v2.x, acc.x); acc.y = fmaf(q2, v2.y, acc.y);
        acc.z = fmaf(q2, v2.z, acc.z); acc.w = fmaf(q2, v2.w, acc.w);
        acc.x = fmaf(q3, v3.x, acc.x); acc.y = fmaf(q3, v3.y, acc.y);
        acc.z = fmaf(q3, v3.z, acc.z); acc.w = fmaf(q3, v3.w, acc.w);
      }
      acc.x += __shfl_xor(acc.x, 16); acc.y += __shfl_xor(acc.y, 16);
      acc.z += __shfl_xor(acc.z, 16); acc.w += __shfl_xor(acc.w, 16);
      acc.x += __shfl_xor(acc.x, 32); acc.y += __shfl_xor(acc.y, 32);
      acc.z += __shfl_xor(acc.z, 32); acc.w += __shfl_xor(acc.w, 32);
      float cx = __shfl(acc.x, lane >> 2);
      float cy = __shfl(acc.y, lane >> 2);
      float cz = __shfl(acc.z, lane >> 2);
      float cw = __shfl(acc.w, lane >> 2);
      int cmp = lane & 3;
      v = (cmp == 0) ? cx : (cmp == 1) ? cy : (cmp == 2) ? cz : cw;
      v /= ssum;
    }
    v = (v > 0.f) ? v : expm1f(v);  // ELU
    hf[((size_t)i << 6) + lane] = v;
    float gacc = 0.f;
#pragma unroll
    for (int k = 0; k < 64; ++k)
      gacc = fmaf(__shfl(v, k), Ws[k * 64 + lane], gacc);
    g[((size_t)i << 6) + lane] = gacc;
  }

  // ---- grid barrier 2 (hf/g ready) ----
  __syncthreads();
  __threadfence();
  if (t == 0) {
    __hip_atomic_fetch_add(&barrier[1], 1, __ATOMIC_ACQ_REL, __HIP_MEMORY_SCOPE_AGENT);
    while (__hip_atomic_load(&barrier[1], __ATOMIC_ACQUIRE, __HIP_MEMORY_SCOPE_AGENT) <
           TAIL_BLOCKS)
      __builtin_amdgcn_s_sleep(32);
  }
  __syncthreads();

  // ---- phase 3: pairwise scores, 256 pairs/block ----
#pragma unroll
  for (int rep = 0; rep < 8; ++rep) {
    int p = blockIdx.x * 256 + wv * 32 + rep * 4 + sg;
    int i1 = p1[p], i2 = p2[p];
    float4 ga = *(const float4*)(g + ((size_t)i1 << 6) + sl * 4);
    float4 hb = *(const float4*)(hf + ((size_t)i2 << 6) + sl * 4);
    float s = ga.x * hb.x + ga.y * hb.y + ga.z * hb.z + ga.w * hb.w;
#pragma unroll
    for (int off = 8; off; off >>= 1) s += __shfl_xor(s, off);
    if (sl == 0) out[p] = s;
  }
}

extern "C" void kernel_launch(void* const* d_in, const int* in_sizes, int n_in,
                              void* d_out, int out_size, void* d_ws, size_t ws_size,
                              hipStream_t stream) {
  const float* x       = (const float*)d_in[0];
  const float* adj     = (const float*)d_in[1];
  const float* W_heads = (const float*)d_in[2];
  const float* a_heads = (const float*)d_in[3];
  const float* W_out   = (const float*)d_in[4];
  const float* a_out   = (const float*)d_in[5];
  const float* W_score = (const float*)d_in[6];
  const int* p1        = (const int*)d_in[7];
  const int* p2        = (const int*)d_in[8];
  float* out           = (float*)d_out;

  char* ws = (char*)d_ws;
  size_t off = 0;
  auto alloc = [&](size_t bytes) -> void* {
    void* p = ws + off;
    off += (bytes + 255) & ~(size_t)255;
    return p;
  };
  int*   counts = (int*)alloc((size_t)N * 4);
  int*   cols   = (int*)alloc((size_t)N * CAP * 4);
  unsigned short* wt1hi = (unsigned short*)alloc((size_t)512 * 512 * 2);
  unsigned short* wt1lo = (unsigned short*)alloc((size_t)512 * 512 * 2);
  unsigned short* wt2hi = (unsigned short*)alloc((size_t)64 * 512 * 2);
  unsigned short* wt2lo = (unsigned short*)alloc((size_t)64 * 512 * 2);
  float* Wh1    = (float*)alloc((size_t)NHEADS * N * 64 * 4);  // head-major
  float* es1    = (float*)alloc((size_t)NHEADS * N * 4);
  float* ed1    = (float*)alloc((size_t)NHEADS * N * 4);
  float* cpart1 = (float*)alloc((size_t)NHEADS * 32 * 64 * 4);
  unsigned short* h1hi = (unsigned short*)alloc((size_t)N * 512 * 2);
  unsigned short* h1lo = (unsigned short*)alloc((size_t)N * 512 * 2);
  float* Wh2    = (float*)alloc((size_t)N * 64 * 4);
  float* es2    = (float*)alloc((size_t)N * 4);
  float* ed2    = (float*)alloc((size_t)N * 4);
  float* cpart2 = (float*)alloc((size_t)32 * 64 * 4);
  float* hf     = (float*)alloc((size_t)N * 64 * 4);
  float* g      = (float*)alloc((size_t)N * 64 * 4);
  int*   barrier = (int*)alloc(256);

  // K1: weight prep + barrier reset
  prep_wt<<<576, 256, 0, stream>>>(W_heads, W_out, wt1hi, wt1lo, wt2hi, wt2lo,
                                   barrier);

  // K2: layer-1 GEMM (256 blocks) ∥ ballot CSR (512 blocks)
  front<<<GEMM_BLOCKS + CSR_BLOCKS, 512, 0, stream>>>(
      x, adj, wt1hi, wt1lo, a_heads, Wh1, es1, ed1, cpart1, counts, cols);

  // K3: layer-1 attention -> h1 bf16 hi/lo
  gat_attn_l1<<<(N / 4) * NHEADS, 256, 0, stream>>>(Wh1, es1, ed1, counts, cols,
                                                    cpart1, h1hi, h1lo);

  // K4: fused tail — layer-2 GEMM + attention + score GEMM + pair scores
  tail2<<<TAIL_BLOCKS, 512, 0, stream>>>(h1hi, h1lo, wt2hi, wt2lo, a_out,
                                         Wh2, es2, ed2, cpart2, counts, cols,
                                         W_score, p1, p2, hf, g, out, barrier);
}

// Round 16
// 84.814 us; speedup vs baseline: 2.4993x; 2.4993x over previous
//
#include <hip/hip_runtime.h>
#include <math.h>

#define N 4096
#define NFEAT 512
#define NHID 64
#define NHEADS 8
#define P_PAIRS 65536
#define CAP 128
#define LRELU_ALPHA 0.2f
#define GEMM_BLOCKS 256

typedef short bf16x8 __attribute__((ext_vector_type(8)));
typedef float f32x4 __attribute__((ext_vector_type(4)));

__device__ __forceinline__ unsigned short f2bf(float f) {
  unsigned u = __float_as_uint(f);
  u = u + 0x7FFFu + ((u >> 16) & 1u);  // round-to-nearest-even
  return (unsigned short)(u >> 16);
}
__device__ __forceinline__ float bf2f(unsigned short h) {
  return __uint_as_float(((unsigned)h) << 16);
}

// LDS swizzle for [row][32-short] tiles (r8): conflict-free fragment reads.
__device__ __forceinline__ int swz(int row, int s) {
  int sl = ((row & 7) * 32 + s) ^ ((row & 7) << 3);
  return (row >> 3) * 256 + sl;
}

// ---------------- K1: weight transpose/split (r12-proven) -------------------
__global__ __launch_bounds__(256) void prep_wt(const float* __restrict__ W1,
                                               const float* __restrict__ W2,
                                               unsigned short* __restrict__ w1hi,
                                               unsigned short* __restrict__ w1lo,
                                               unsigned short* __restrict__ w2hi,
                                               unsigned short* __restrict__ w2lo) {
  int c = blockIdx.x;
  const float* W;
  unsigned short *hiP, *loP;
  if (c < 512) { W = W1; hiP = w1hi; loP = w1lo; }
  else         { W = W2; hiP = w2hi; loP = w2lo; c -= 512; }
  const float* Wp = W + (size_t)(c >> 6) * 512 * 64 + (c & 63);
  for (int k = threadIdx.x; k < 512; k += 256) {
    float v = Wp[(size_t)k * 64];
    unsigned short hb = f2bf(v);
    hiP[(size_t)c * 512 + k] = hb;
    loP[(size_t)c * 512 + k] = f2bf(v - bf2f(hb));
  }
}

// ---------------- GEMM body (device fn): split-precision bf16 MFMA ---------
// Tile 128x64, 8 waves. LDS XOR-swizzled, dbuf, fused e/colsum epilogue.
template <bool F32A>
__device__ __forceinline__ void gemm_body(unsigned short* As, unsigned short* Bs,
                                          int mIdx, int head,
                                          const float* __restrict__ Af,
                                          const unsigned short* __restrict__ Ahi,
                                          const unsigned short* __restrict__ Alo,
                                          const unsigned short* __restrict__ Bhi,
                                          const unsigned short* __restrict__ Blo,
                                          const float* __restrict__ aVec,
                                          float* __restrict__ C,
                                          float* __restrict__ esrc,
                                          float* __restrict__ edst,
                                          float* __restrict__ cpart) {
  const int t = threadIdx.x;
  const int m0 = mIdx * 128;
  const int c0 = head * 64;
  const int lane = t & 63, wave = t >> 6;
  const int g = lane >> 4, r = lane & 15;
  const int wm = (wave >> 1) * 32;
  const int wn = (wave & 1) * 32;
  const int sar = t >> 2, sak = (t & 3) * 8;
  const int tb = t & 255;
  const int sbr = tb >> 2, sbk = (tb & 3) * 8;
  const unsigned short* Bsel = (t < 256) ? Bhi : Blo;
  const int bhalf = (t < 256) ? 0 : 1;
  const int idxA = swz(sar, sak);
  const int idxB = swz(sbr, sbk);
  const size_t aOff = (size_t)(m0 + sar) * 512 + sak;
  const size_t bOff = (size_t)(c0 + sbr) * 512 + sbk;
  const f32x4 z = {0.f, 0.f, 0.f, 0.f};
  f32x4 acc[2][2];
  acc[0][0] = z; acc[0][1] = z; acc[1][0] = z; acc[1][1] = z;

  int4 a0, a1, b0;
  auto loadRegs = [&](int kb) {
    if constexpr (F32A) {
      float4 v0 = *(const float4*)(Af + aOff + kb);
      float4 v1 = *(const float4*)(Af + aOff + kb + 4);
      unsigned h0 = f2bf(v0.x), h1 = f2bf(v0.y), h2 = f2bf(v0.z), h3 = f2bf(v0.w);
      unsigned h4 = f2bf(v1.x), h5 = f2bf(v1.y), h6 = f2bf(v1.z), h7 = f2bf(v1.w);
      unsigned l0 = f2bf(v0.x - bf2f(h0)), l1 = f2bf(v0.y - bf2f(h1));
      unsigned l2 = f2bf(v0.z - bf2f(h2)), l3 = f2bf(v0.w - bf2f(h3));
      unsigned l4 = f2bf(v1.x - bf2f(h4)), l5 = f2bf(v1.y - bf2f(h5));
      unsigned l6 = f2bf(v1.z - bf2f(h6)), l7 = f2bf(v1.w - bf2f(h7));
      a0.x = h0 | (h1 << 16); a0.y = h2 | (h3 << 16);
      a0.z = h4 | (h5 << 16); a0.w = h6 | (h7 << 16);
      a1.x = l0 | (l1 << 16); a1.y = l2 | (l3 << 16);
      a1.z = l4 | (l5 << 16); a1.w = l6 | (l7 << 16);
    } else {
      a0 = *(const int4*)(Ahi + aOff + kb);
      a1 = *(const int4*)(Alo + aOff + kb);
    }
    b0 = *(const int4*)(Bsel + bOff + kb);
  };
  auto storeLds = [&](int buf) {
    *(int4*)(&As[(buf * 2 + 0) * 4096 + idxA]) = a0;
    *(int4*)(&As[(buf * 2 + 1) * 4096 + idxA]) = a1;
    *(int4*)(&Bs[(buf * 2 + bhalf) * 2048 + idxB]) = b0;
  };

  loadRegs(0);
  storeLds(0);
  __syncthreads();

  for (int ch = 0; ch < 16; ++ch) {
    const int cur = ch & 1;
    if (ch < 15) loadRegs((ch + 1) * 32);
    bf16x8 ah[2], al[2], bh[2], bl[2];
#pragma unroll
    for (int f = 0; f < 2; ++f) {
      int ia = swz(wm + f * 16 + r, 8 * g);
      int ib = swz(wn + f * 16 + r, 8 * g);
      ah[f] = *(const bf16x8*)(&As[(cur * 2 + 0) * 4096 + ia]);
      al[f] = *(const bf16x8*)(&As[(cur * 2 + 1) * 4096 + ia]);
      bh[f] = *(const bf16x8*)(&Bs[(cur * 2 + 0) * 2048 + ib]);
      bl[f] = *(const bf16x8*)(&Bs[(cur * 2 + 1) * 2048 + ib]);
    }
#pragma unroll
    for (int i = 0; i < 2; ++i)
#pragma unroll
      for (int j = 0; j < 2; ++j) {
        acc[i][j] = __builtin_amdgcn_mfma_f32_16x16x32_bf16(ah[i], bh[j], acc[i][j], 0, 0, 0);
        acc[i][j] = __builtin_amdgcn_mfma_f32_16x16x32_bf16(al[i], bh[j], acc[i][j], 0, 0, 0);
        acc[i][j] = __builtin_amdgcn_mfma_f32_16x16x32_bf16(ah[i], bl[j], acc[i][j], 0, 0, 0);
      }
    if (ch < 15) {
      storeLds(cur ^ 1);
      __syncthreads();
    }
  }

  // epilogue: C tile via LDS, esrc/edst shfl-dots, per-block column partials
  __syncthreads();
  float* Cs = (float*)As;  // 32 KB = 128x64 f32
#pragma unroll
  for (int i = 0; i < 2; ++i)
#pragma unroll
    for (int j = 0; j < 2; ++j)
#pragma unroll
      for (int q = 0; q < 4; ++q)
        Cs[(wm + i * 16 + 4 * g + q) * 64 + wn + j * 16 + r] = acc[i][j][q];
  __syncthreads();
  float* Cp = C + ((size_t)head * N + m0) * 64;
  const float* aV = aVec + (size_t)head * 128;
  float as_ = aV[lane], ad_ = aV[64 + lane];
  float cs = 0.f;
#pragma unroll
  for (int rr = 0; rr < 16; ++rr) {
    int row = wave * 16 + rr;
    float v = Cs[row * 64 + lane];
    Cp[(size_t)row * 64 + lane] = v;
    cs += v;
    float s = v * as_, d = v * ad_;
#pragma unroll
    for (int off = 32; off; off >>= 1) {
      s += __shfl_xor(s, off);
      d += __shfl_xor(d, off);
    }
    if (lane == 0) {
      esrc[(size_t)head * N + m0 + row] = s;
      edst[(size_t)head * N + m0 + row] = d;
    }
  }
  float* red = (float*)Bs;  // free after MFMA loop
  red[wave * 64 + lane] = cs;
  __syncthreads();
  if (wave == 0) {
    float s = 0.f;
#pragma unroll
    for (int j = 0; j < 8; ++j) s += red[j * 64 + lane];
    cpart[((size_t)head * 32 + mIdx) * 64 + lane] = s;
  }
}

// ---------------- K2: front — layer-1 GEMM blocks + CSR blocks (overlap) ---
__global__ __launch_bounds__(512) void front(const float* __restrict__ x,
                                             const float* __restrict__ adj,
                                             const unsigned short* __restrict__ w1hi,
                                             const unsigned short* __restrict__ w1lo,
                                             const float* __restrict__ aVec,
                                             float* __restrict__ Wh1,
                                             float* __restrict__ es1,
                                             float* __restrict__ ed1,
                                             float* __restrict__ cpart1,
                                             int* __restrict__ counts,
                                             int* __restrict__ cols) {
  __shared__ unsigned short As[2 * 2 * 4096];
  __shared__ unsigned short Bs[2 * 2 * 2048];
  int b = blockIdx.x;
  if (b >= GEMM_BLOCKS) {
    // CSR: one adj row per block, 512 threads
    int row = b - GEMM_BLOCKS;
    int* cntp = (int*)As;
    if (threadIdx.x == 0) *cntp = 0;
    __syncthreads();
    const float4* arow = (const float4*)(adj + (size_t)row * N);
    for (int c4 = threadIdx.x; c4 < N / 4; c4 += 512) {
      float4 v = arow[c4];
      int base = c4 * 4;
      if (v.x > 0.f) { int k = atomicAdd(cntp, 1); if (k < CAP) cols[(size_t)row * CAP + k] = base; }
      if (v.y > 0.f) { int k = atomicAdd(cntp, 1); if (k < CAP) cols[(size_t)row * CAP + k] = base + 1; }
      if (v.z > 0.f) { int k = atomicAdd(cntp, 1); if (k < CAP) cols[(size_t)row * CAP + k] = base + 2; }
      if (v.w > 0.f) { int k = atomicAdd(cntp, 1); if (k < CAP) cols[(size_t)row * CAP + k] = base + 3; }
    }
    __syncthreads();
    if (threadIdx.x == 0) counts[row] = (*cntp < CAP) ? *cntp : CAP;
    return;
  }
  gemm_body<true>(As, Bs, b & 31, b >> 5, x, nullptr, nullptr, w1hi, w1lo,
                  aVec, Wh1, es1, ed1, cpart1);
}

// ---------------- K3: layer-1 attention, wave per (node,head) --------------
__global__ __launch_bounds__(256) void gat_attn_l1(const float* __restrict__ Wh,
                                                   const float* __restrict__ esrc,
                                                   const float* __restrict__ edst,
                                                   const int* __restrict__ counts,
                                                   const int* __restrict__ cols,
                                                   const float* __restrict__ cpart1,
                                                   unsigned short* __restrict__ hhi,
                                                   unsigned short* __restrict__ hlo) {
  int h = blockIdx.x & 7;
  int wv = threadIdx.x >> 6;
  int lane = threadIdx.x & 63;
  int sg = lane >> 4, sl = lane & 15;
  int i = (blockIdx.x >> 3) * 4 + wv;
  int cnt = counts[i];
  __shared__ int jls[4][CAP];
  __shared__ float pls[4][CAP];
  const float* WhH = Wh + (size_t)h * N * 64;
  float4 acc = {0.f, 0.f, 0.f, 0.f};
  if (cnt == 0) {
    float4 sv = {0.f, 0.f, 0.f, 0.f};
    for (int j = 0; j < 32; ++j) {
      float4 p = *(const float4*)(cpart1 + ((size_t)h * 32 + j) * 64 + 4 * sl);
      sv.x += p.x; sv.y += p.y; sv.z += p.z; sv.w += p.w;
    }
    acc.x = sv.x * (1.0f / N); acc.y = sv.y * (1.0f / N);
    acc.z = sv.z * (1.0f / N); acc.w = sv.w * (1.0f / N);
  } else {
    const int* cl = cols + (size_t)i * CAP;
    jls[wv][lane] = (lane < cnt) ? cl[lane] : 0;
    jls[wv][lane + 64] = (lane + 64 < cnt) ? cl[lane + 64] : 0;
    float ei = esrc[h * N + i];
    const float* ed = edst + (size_t)h * N;
    float e0 = -1e30f, e1 = -1e30f;
    if (lane < cnt) {
      float e = ei + ed[jls[wv][lane]];
      e0 = (e > 0.f) ? e : LRELU_ALPHA * e;
    }
    if (lane + 64 < cnt) {
      float e = ei + ed[jls[wv][lane + 64]];
      e1 = (e > 0.f) ? e : LRELU_ALPHA * e;
    }
    float m = fmaxf(e0, e1);
#pragma unroll
    for (int off = 32; off; off >>= 1) m = fmaxf(m, __shfl_xor(m, off));
    float p0 = (lane < cnt) ? __expf(e0 - m) : 0.f;
    float p1 = (lane + 64 < cnt) ? __expf(e1 - m) : 0.f;
    float ssum = p0 + p1;
#pragma unroll
    for (int off = 32; off; off >>= 1) ssum += __shfl_xor(ssum, off);
    pls[wv][lane] = p0;
    pls[wv][lane + 64] = p1;  // own-wave write->read
    int L = (cnt + 15) & ~15;
    for (int k = 0; k < L; k += 16) {
      int j0 = jls[wv][k + sg];
      int j1 = jls[wv][k + 4 + sg];
      int j2 = jls[wv][k + 8 + sg];
      int j3 = jls[wv][k + 12 + sg];
      float4 v0 = *(const float4*)(WhH + ((size_t)j0 << 6) + 4 * sl);
      float4 v1 = *(const float4*)(WhH + ((size_t)j1 << 6) + 4 * sl);
      float4 v2 = *(const float4*)(WhH + ((size_t)j2 << 6) + 4 * sl);
      float4 v3 = *(const float4*)(WhH + ((size_t)j3 << 6) + 4 * sl);
      float q0 = pls[wv][k + sg];
      float q1 = pls[wv][k + 4 + sg];
      float q2 = pls[wv][k + 8 + sg];
      float q3 = pls[wv][k + 12 + sg];
      acc.x = fmaf(q0, v0.x, acc.x); acc.y = fmaf(q0, v0.y, acc.y);
      acc.z = fmaf(q0, v0.z, acc.z); acc.w = fmaf(q0, v0.w, acc.w);
      acc.x = fmaf(q1, v1.x, acc.x); acc.y = fmaf(q1, v1.y, acc.y);
      acc.z = fmaf(q1, v1.z, acc.z); acc.w = fmaf(q1, v1.w, acc.w);
      acc.x = fmaf(q2, v2.x, acc.x); acc.y = fmaf(q2, v2.y, acc.y);
      acc.z = fmaf(q2, v2.z, acc.z); acc.w = fmaf(q2, v2.w, acc.w);
      acc.x = fmaf(q3, v3.x, acc.x); acc.y = fmaf(q3, v3.y, acc.y);
      acc.z = fmaf(q3, v3.z, acc.z); acc.w = fmaf(q3, v3.w, acc.w);
    }
    acc.x += __shfl_xor(acc.x, 16); acc.y += __shfl_xor(acc.y, 16);
    acc.z += __shfl_xor(acc.z, 16); acc.w += __shfl_xor(acc.w, 16);
    acc.x += __shfl_xor(acc.x, 32); acc.y += __shfl_xor(acc.y, 32);
    acc.z += __shfl_xor(acc.z, 32); acc.w += __shfl_xor(acc.w, 32);
    float inv = 1.0f / ssum;
    acc.x *= inv; acc.y *= inv; acc.z *= inv; acc.w *= inv;
  }
  if (sg == 0) {
    acc.x = (acc.x > 0.f) ? acc.x : expm1f(acc.x);
    acc.y = (acc.y > 0.f) ? acc.y : expm1f(acc.y);
    acc.z = (acc.z > 0.f) ? acc.z : expm1f(acc.z);
    acc.w = (acc.w > 0.f) ? acc.w : expm1f(acc.w);
    ushort4 hi4, lo4;
    hi4.x = f2bf(acc.x); lo4.x = f2bf(acc.x - bf2f(hi4.x));
    hi4.y = f2bf(acc.y); lo4.y = f2bf(acc.y - bf2f(hi4.y));
    hi4.z = f2bf(acc.z); lo4.z = f2bf(acc.z - bf2f(hi4.z));
    hi4.w = f2bf(acc.w); lo4.w = f2bf(acc.w - bf2f(hi4.w));
    size_t o = (size_t)i * 512 + h * 64 + 4 * sl;
    *(ushort4*)(hhi + o) = hi4;
    *(ushort4*)(hlo + o) = lo4;
  }
}

// ---------------- K4: mid — layer-2 GEMM + fused e/colsum ------------------
__global__ __launch_bounds__(512) void mid(const unsigned short* __restrict__ h1hi,
                                           const unsigned short* __restrict__ h1lo,
                                           const unsigned short* __restrict__ w2hi,
                                           const unsigned short* __restrict__ w2lo,
                                           const float* __restrict__ aVec,
                                           float* __restrict__ Wh2,
                                           float* __restrict__ es2,
                                           float* __restrict__ ed2,
                                           float* __restrict__ cpart2) {
  __shared__ unsigned short As[2 * 2 * 4096];
  __shared__ unsigned short Bs[2 * 2 * 2048];
  gemm_body<false>(As, Bs, blockIdx.x, 0, nullptr, h1hi, h1lo, w2hi, w2lo,
                   aVec, Wh2, es2, ed2, cpart2);
}

// ---------------- K5: layer-2 attention + fused g = hf @ W_score -----------
__global__ __launch_bounds__(256) void gat_attn_l2(const float* __restrict__ Wh,
                                                   const float* __restrict__ esrc,
                                                   const float* __restrict__ edst,
                                                   const int* __restrict__ counts,
                                                   const int* __restrict__ cols,
                                                   const float* __restrict__ cpart2,
                                                   const float* __restrict__ Wsc,
                                                   float* __restrict__ hf,
                                                   float* __restrict__ g) {
  __shared__ float Ws[64][64];
  int t = threadIdx.x;
#pragma unroll
  for (int j = 0; j < 4; ++j) {
    int q = t + j * 256;
    int k = q >> 4, cq = (q & 15) * 4;
    *(float4*)(&Ws[k][cq]) = *(const float4*)(Wsc + k * 64 + cq);
  }
  __syncthreads();
  int wv = t >> 6;
  int lane = t & 63;
  int sg = lane >> 4, sl = lane & 15;
  int i = (blockIdx.x << 2) + wv;
  int cnt = counts[i];
  __shared__ int jls[4][CAP];
  __shared__ float pls[4][CAP];
  float v;
  if (cnt == 0) {
    float s = 0.f;
    for (int j = 0; j < 32; ++j) s += cpart2[(size_t)j * 64 + lane];
    v = s * (1.0f / N);
  } else {
    const int* cl = cols + (size_t)i * CAP;
    jls[wv][lane] = (lane < cnt) ? cl[lane] : 0;
    jls[wv][lane + 64] = (lane + 64 < cnt) ? cl[lane + 64] : 0;
    float ei = esrc[i];
    float e0 = -1e30f, e1 = -1e30f;
    if (lane < cnt) {
      float e = ei + edst[jls[wv][lane]];
      e0 = (e > 0.f) ? e : LRELU_ALPHA * e;
    }
    if (lane + 64 < cnt) {
      float e = ei + edst[jls[wv][lane + 64]];
      e1 = (e > 0.f) ? e : LRELU_ALPHA * e;
    }
    float m = fmaxf(e0, e1);
#pragma unroll
    for (int off = 32; off; off >>= 1) m = fmaxf(m, __shfl_xor(m, off));
    float p0 = (lane < cnt) ? __expf(e0 - m) : 0.f;
    float p1 = (lane + 64 < cnt) ? __expf(e1 - m) : 0.f;
    float ssum = p0 + p1;
#pragma unroll
    for (int off = 32; off; off >>= 1) ssum += __shfl_xor(ssum, off);
    pls[wv][lane] = p0;
    pls[wv][lane + 64] = p1;
    float4 acc = {0.f, 0.f, 0.f, 0.f};
    int L = (cnt + 15) & ~15;
    for (int k = 0; k < L; k += 16) {
      int j0 = jls[wv][k + sg];
      int j1 = jls[wv][k + 4 + sg];
      int j2 = jls[wv][k + 8 + sg];
      int j3 = jls[wv][k + 12 + sg];
      float4 v0 = *(const float4*)(Wh + ((size_t)j0 << 6) + 4 * sl);
      float4 v1 = *(const float4*)(Wh + ((size_t)j1 << 6) + 4 * sl);
      float4 v2 = *(const float4*)(Wh + ((size_t)j2 << 6) + 4 * sl);
      float4 v3 = *(const float4*)(Wh + ((size_t)j3 << 6) + 4 * sl);
      float q0 = pls[wv][k + sg];
      float q1 = pls[wv][k + 4 + sg];
      float q2 = pls[wv][k + 8 + sg];
      float q3 = pls[wv][k + 12 + sg];
      acc.x = fmaf(q0, v0.x, acc.x); acc.y = fmaf(q0, v0.y, acc.y);
      acc.z = fmaf(q0, v0.z, acc.z); acc.w = fmaf(q0, v0.w, acc.w);
      acc.x = fmaf(q1, v1.x, acc.x); acc.y = fmaf(q1, v1.y, acc.y);
      acc.z = fmaf(q1, v1.z, acc.z); acc.w = fmaf(q1, v1.w, acc.w);
      acc.x = fmaf(q2, v2.x, acc.x); acc.y = fmaf(q2, v2.y, acc.y);
      acc.z = fmaf(q2, v2.z, acc.z); acc.w = fmaf(q2, v2.w, acc.w);
      acc.x = fmaf(q3, v3.x, acc.x); acc.y = fmaf(q3, v3.y, acc.y);
      acc.z = fmaf(q3, v3.z, acc.z); acc.w = fmaf(q3, v3.w, acc.w);
    }
    acc.x += __shfl_xor(acc.x, 16); acc.y += __shfl_xor(acc.y, 16);
    acc.z += __shfl_xor(acc.z, 16); acc.w += __shfl_xor(acc.w, 16);
    acc.x += __shfl_xor(acc.x, 32); acc.y += __shfl_xor(acc.y, 32);
    acc.z += __shfl_xor(acc.z, 32); acc.w += __shfl_xor(acc.w, 32);
    float cx = __shfl(acc.x, lane >> 2);
    float cy = __shfl(acc.y, lane >> 2);
    float cz = __shfl(acc.z, lane >> 2);
    float cw = __shfl(acc.w, lane >> 2);
    int cmp = lane & 3;
    v = (cmp == 0) ? cx : (cmp == 1) ? cy : (cmp == 2) ? cz : cw;
    v /= ssum;
  }
  v = (v > 0.f) ? v : expm1f(v);  // ELU
  hf[((size_t)i << 6) + lane] = v;
  float gacc = 0.f;
#pragma unroll
  for (int k = 0; k < 64; ++k)
    gacc = fmaf(__shfl(v, k), Ws[k][lane], gacc);
  g[((size_t)i << 6) + lane] = gacc;
}

// ---------------- K6: pairwise bilinear scores (4 pairs/wave, float4) ------
__global__ __launch_bounds__(256) void score_quad(const float* __restrict__ g,
                                                  const float* __restrict__ hf,
                                                  const int* __restrict__ p1,
                                                  const int* __restrict__ p2,
                                                  float* __restrict__ out) {
  int w = threadIdx.x >> 6;
  int lane = threadIdx.x & 63;
  int sub = lane >> 4, sl = lane & 15;
  int p = (((blockIdx.x << 2) + w) << 2) + sub;
  int i1 = p1[p], i2 = p2[p];
  float4 ga = *(const float4*)(g + ((size_t)i1 << 6) + sl * 4);
  float4 hb = *(const float4*)(hf + ((size_t)i2 << 6) + sl * 4);
  float v = ga.x * hb.x + ga.y * hb.y + ga.z * hb.z + ga.w * hb.w;
#pragma unroll
  for (int off = 8; off; off >>= 1) v += __shfl_xor(v, off);
  if (sl == 0) out[p] = v;
}

extern "C" void kernel_launch(void* const* d_in, const int* in_sizes, int n_in,
                              void* d_out, int out_size, void* d_ws, size_t ws_size,
                              hipStream_t stream) {
  const float* x       = (const float*)d_in[0];
  const float* adj     = (const float*)d_in[1];
  const float* W_heads = (const float*)d_in[2];
  const float* a_heads = (const float*)d_in[3];
  const float* W_out   = (const float*)d_in[4];
  const float* a_out   = (const float*)d_in[5];
  const float* W_score = (const float*)d_in[6];
  const int* p1        = (const int*)d_in[7];
  const int* p2        = (const int*)d_in[8];
  float* out           = (float*)d_out;

  char* ws = (char*)d_ws;
  size_t off = 0;
  auto alloc = [&](size_t bytes) -> void* {
    void* p = ws + off;
    off += (bytes + 255) & ~(size_t)255;
    return p;
  };
  int*   counts = (int*)alloc((size_t)N * 4);
  int*   cols   = (int*)alloc((size_t)N * CAP * 4);
  unsigned short* wt1hi = (unsigned short*)alloc((size_t)512 * 512 * 2);
  unsigned short* wt1lo = (unsigned short*)alloc((size_t)512 * 512 * 2);
  unsigned short* wt2hi = (unsigned short*)alloc((size_t)64 * 512 * 2);
  unsigned short* wt2lo = (unsigned short*)alloc((size_t)64 * 512 * 2);
  float* Wh1    = (float*)alloc((size_t)NHEADS * N * 64 * 4);  // head-major
  float* es1    = (float*)alloc((size_t)NHEADS * N * 4);
  float* ed1    = (float*)alloc((size_t)NHEADS * N * 4);
  float* cpart1 = (float*)alloc((size_t)NHEADS * 32 * 64 * 4);
  unsigned short* h1hi = (unsigned short*)alloc((size_t)N * 512 * 2);
  unsigned short* h1lo = (unsigned short*)alloc((size_t)N * 512 * 2);
  float* Wh2    = (float*)alloc((size_t)N * 64 * 4);
  float* es2    = (float*)alloc((size_t)N * 4);
  float* ed2    = (float*)alloc((size_t)N * 4);
  float* cpart2 = (float*)alloc((size_t)32 * 64 * 4);
  float* hf     = (float*)alloc((size_t)N * 64 * 4);
  float* g      = (float*)alloc((size_t)N * 64 * 4);

  // K1: weight prep
  prep_wt<<<576, 256, 0, stream>>>(W_heads, W_out, wt1hi, wt1lo, wt2hi, wt2lo);

  // K2: layer-1 GEMM (256 blocks) overlapped with CSR build (4096 blocks)
  front<<<GEMM_BLOCKS + N, 512, 0, stream>>>(x, adj, wt1hi, wt1lo, a_heads,
                                             Wh1, es1, ed1, cpart1, counts, cols);

  // K3: layer-1 attention -> h1 bf16 hi/lo
  gat_attn_l1<<<(N / 4) * NHEADS, 256, 0, stream>>>(Wh1, es1, ed1, counts, cols,
                                                    cpart1, h1hi, h1lo);

  // K4: layer-2 GEMM + fused e/colsum
  mid<<<32, 512, 0, stream>>>(h1hi, h1lo, wt2hi, wt2lo, a_out, Wh2, es2, ed2,
                              cpart2);

  // K5: layer-2 attention + fused score GEMM
  gat_attn_l2<<<N / 4, 256, 0, stream>>>(Wh2, es2, ed2, counts, cols, cpart2,
                                         W_score, hf, g);

  // K6: pairwise scores
  score_quad<<<P_PAIRS / 16, 256, 0, stream>>>(g, hf, p1, p2, out);
}